// Round 1
// baseline (355.358 us; speedup 1.0000x reference)
//
#include <hip/hip_runtime.h>

#define H 128
#define EPS 1e-12f

// Kernel 1: per-node inverse L2 norm. One 64-lane wave per row; lane l reads
// float2 at elements {2l, 2l+1} (coalesced 512B per row).
__global__ void inv_norm_kernel(const float* __restrict__ emb,
                                float* __restrict__ inv,
                                int n_nodes) {
    int row = blockIdx.x * (blockDim.x >> 6) + (threadIdx.x >> 6);
    if (row >= n_nodes) return;
    int lane = threadIdx.x & 63;
    const float2* p = (const float2*)(emb + (size_t)row * H);
    float2 v = p[lane];
    float ss = v.x * v.x + v.y * v.y;
#pragma unroll
    for (int off = 32; off; off >>= 1) ss += __shfl_xor(ss, off);
    if (lane == 0) inv[row] = 1.0f / fmaxf(sqrtf(ss), EPS);
}

// Kernel 2: one wave per edge. Gather the two raw emb rows (coalesced 512B
// each), dot with diag d folded in, scale by the two inverse norms + scale.
__global__ void edge_dot_kernel(const float* __restrict__ emb,
                                const float* __restrict__ inv,
                                const int* __restrict__ src,
                                const int* __restrict__ dst,
                                const float* __restrict__ d,
                                const float* __restrict__ scale,
                                float* __restrict__ out,
                                int n_edges) {
    int edge = blockIdx.x * (blockDim.x >> 6) + (threadIdx.x >> 6);
    if (edge >= n_edges) return;
    int lane = threadIdx.x & 63;

    int s = src[edge];
    int t = dst[edge];

    const float2* ps = (const float2*)(emb + (size_t)s * H);
    const float2* pt = (const float2*)(emb + (size_t)t * H);
    float2 dv = ((const float2*)d)[lane];

    float2 a = ps[lane];
    float2 b = pt[lane];
    float p = a.x * dv.x * b.x + a.y * dv.y * b.y;
#pragma unroll
    for (int off = 32; off; off >>= 1) p += __shfl_xor(p, off);

    if (lane == 0) {
        out[edge] = p * inv[s] * inv[t] * scale[0];
    }
}

extern "C" void kernel_launch(void* const* d_in, const int* in_sizes, int n_in,
                              void* d_out, int out_size, void* d_ws, size_t ws_size,
                              hipStream_t stream) {
    const float* emb   = (const float*)d_in[0];
    const int*   src   = (const int*)d_in[1];
    const int*   dst   = (const int*)d_in[2];
    const float* d     = (const float*)d_in[3];
    const float* scale = (const float*)d_in[4];
    float* out = (float*)d_out;
    float* inv = (float*)d_ws;  // n_nodes floats (400 KB)

    int n_nodes = in_sizes[0] / H;
    int n_edges = in_sizes[1];

    // 4 waves (rows) per 256-thread block
    int blocks1 = (n_nodes + 3) / 4;
    inv_norm_kernel<<<blocks1, 256, 0, stream>>>(emb, inv, n_nodes);

    // 4 waves (edges) per 256-thread block
    int blocks2 = (n_edges + 3) / 4;
    edge_dot_kernel<<<blocks2, 256, 0, stream>>>(emb, inv, src, dst, d, scale,
                                                 out, n_edges);
}

// Round 2
// 124.069 us; speedup vs baseline: 2.8642x; 2.8642x over previous
//
#include <hip/hip_runtime.h>

#define H 128
#define EPS 1e-12f

static __device__ __forceinline__ float bf_lo(unsigned int v) {
    return __uint_as_float(v << 16);
}
static __device__ __forceinline__ float bf_hi(unsigned int v) {
    return __uint_as_float(v & 0xFFFF0000u);
}
static __device__ __forceinline__ unsigned int f2bf_rne(float f) {
    unsigned int u = __float_as_uint(f);
    return (u + 0x7FFFu + ((u >> 16) & 1u)) >> 16;
}

// ---------------- bf16-pool path ----------------

// Normalize each row to unit L2 norm, quantize to bf16, write 256B/row pool.
// One 64-lane wave per row; lane l handles elements {2l, 2l+1}.
__global__ void norm_quant_kernel(const float* __restrict__ emb,
                                  unsigned int* __restrict__ pool,
                                  int n_nodes) {
    int row = blockIdx.x * (blockDim.x >> 6) + (threadIdx.x >> 6);
    if (row >= n_nodes) return;
    int lane = threadIdx.x & 63;
    const float2* p = (const float2*)(emb + (size_t)row * H);
    float2 v = p[lane];
    float ss = v.x * v.x + v.y * v.y;
#pragma unroll
    for (int off = 32; off; off >>= 1) ss += __shfl_xor(ss, off);
    float inv = 1.0f / fmaxf(sqrtf(ss), EPS);
    unsigned int ua = f2bf_rne(v.x * inv);
    unsigned int ub = f2bf_rne(v.y * inv);
    pool[(size_t)row * 64 + lane] = ua | (ub << 16);
}

// 4 edges per wave, 16 lanes per edge; each lane loads uint4 (8 bf16) per row.
// Grid-stride loop amortizes d/scale loads.
__global__ void edge_dot_bf16_kernel(const uint4* __restrict__ pool,
                                     const int* __restrict__ src,
                                     const int* __restrict__ dst,
                                     const float* __restrict__ d,
                                     const float* __restrict__ scale,
                                     float* __restrict__ out,
                                     int n_edges) {
    int lane = threadIdx.x & 63;
    int sub = lane >> 4;   // which of the 4 edges this wave handles
    int q   = lane & 15;   // 16B chunk within the 256B row

    // d elements 8q .. 8q+7, loaded once
    float4 d0 = ((const float4*)d)[q * 2];
    float4 d1 = ((const float4*)d)[q * 2 + 1];
    float sc = scale[0];

    int waveId = (blockIdx.x * blockDim.x + threadIdx.x) >> 6;
    int nWaves = (gridDim.x * blockDim.x) >> 6;

    for (int ebase = waveId * 4; ebase < n_edges; ebase += nWaves * 4) {
        int e = ebase + sub;
        bool valid = (e < n_edges);
        int s = valid ? src[e] : 0;
        int t = valid ? dst[e] : 0;

        uint4 va = pool[(size_t)s * 16 + q];
        uint4 vb = pool[(size_t)t * 16 + q];

        float p;
        p  = bf_lo(va.x) * d0.x * bf_lo(vb.x);
        p  = fmaf(bf_hi(va.x) * d0.y, bf_hi(vb.x), p);
        p  = fmaf(bf_lo(va.y) * d0.z, bf_lo(vb.y), p);
        p  = fmaf(bf_hi(va.y) * d0.w, bf_hi(vb.y), p);
        p  = fmaf(bf_lo(va.z) * d1.x, bf_lo(vb.z), p);
        p  = fmaf(bf_hi(va.z) * d1.y, bf_hi(vb.z), p);
        p  = fmaf(bf_lo(va.w) * d1.z, bf_lo(vb.w), p);
        p  = fmaf(bf_hi(va.w) * d1.w, bf_hi(vb.w), p);

        // reduce across the 16 lanes of this edge's group
        p += __shfl_xor(p, 1);
        p += __shfl_xor(p, 2);
        p += __shfl_xor(p, 4);
        p += __shfl_xor(p, 8);

        if (q == 0 && valid) out[e] = p * sc;
    }
}

// ---------------- fallback f32 path (R1, proven) ----------------

__global__ void inv_norm_kernel(const float* __restrict__ emb,
                                float* __restrict__ inv,
                                int n_nodes) {
    int row = blockIdx.x * (blockDim.x >> 6) + (threadIdx.x >> 6);
    if (row >= n_nodes) return;
    int lane = threadIdx.x & 63;
    const float2* p = (const float2*)(emb + (size_t)row * H);
    float2 v = p[lane];
    float ss = v.x * v.x + v.y * v.y;
#pragma unroll
    for (int off = 32; off; off >>= 1) ss += __shfl_xor(ss, off);
    if (lane == 0) inv[row] = 1.0f / fmaxf(sqrtf(ss), EPS);
}

__global__ void edge_dot_kernel(const float* __restrict__ emb,
                                const float* __restrict__ inv,
                                const int* __restrict__ src,
                                const int* __restrict__ dst,
                                const float* __restrict__ d,
                                const float* __restrict__ scale,
                                float* __restrict__ out,
                                int n_edges) {
    int edge = blockIdx.x * (blockDim.x >> 6) + (threadIdx.x >> 6);
    if (edge >= n_edges) return;
    int lane = threadIdx.x & 63;
    int s = src[edge];
    int t = dst[edge];
    const float2* ps = (const float2*)(emb + (size_t)s * H);
    const float2* pt = (const float2*)(emb + (size_t)t * H);
    float2 dv = ((const float2*)d)[lane];
    float2 a = ps[lane];
    float2 b = pt[lane];
    float p = a.x * dv.x * b.x + a.y * dv.y * b.y;
#pragma unroll
    for (int off = 32; off; off >>= 1) p += __shfl_xor(p, off);
    if (lane == 0) out[edge] = p * inv[s] * inv[t] * scale[0];
}

extern "C" void kernel_launch(void* const* d_in, const int* in_sizes, int n_in,
                              void* d_out, int out_size, void* d_ws, size_t ws_size,
                              hipStream_t stream) {
    const float* emb   = (const float*)d_in[0];
    const int*   src   = (const int*)d_in[1];
    const int*   dst   = (const int*)d_in[2];
    const float* d     = (const float*)d_in[3];
    const float* scale = (const float*)d_in[4];
    float* out = (float*)d_out;

    int n_nodes = in_sizes[0] / H;
    int n_edges = in_sizes[1];

    size_t pool_bytes = (size_t)n_nodes * H * 2;  // bf16 pool

    if (ws_size >= pool_bytes) {
        unsigned int* pool = (unsigned int*)d_ws;

        int blocks1 = (n_nodes + 3) / 4;  // 4 rows per 256-thread block
        norm_quant_kernel<<<blocks1, 256, 0, stream>>>(emb, pool, n_nodes);

        // grid-stride: 2048 blocks x 4 waves x 4 edges = 32768 edges per sweep
        int blocks2 = 2048;
        edge_dot_bf16_kernel<<<blocks2, 256, 0, stream>>>(
            (const uint4*)pool, src, dst, d, scale, out, n_edges);
    } else {
        float* inv = (float*)d_ws;  // n_nodes floats
        int blocks1 = (n_nodes + 3) / 4;
        inv_norm_kernel<<<blocks1, 256, 0, stream>>>(emb, inv, n_nodes);
        int blocks2 = (n_edges + 3) / 4;
        edge_dot_kernel<<<blocks2, 256, 0, stream>>>(emb, inv, src, dst, d,
                                                     scale, out, n_edges);
    }
}